// Round 3
// baseline (4251.140 us; speedup 1.0000x reference)
//
#include <hip/hip_runtime.h>

// ---------------- problem constants ----------------
#define T_STEPS 512
#define BATCH_N 256
#define IDIM    128
#define NDIM    1024
#define ODIM    10

// decomposition: 16 batch-groups (16 rows) x 16 n-slices (64 cols) = 256 WGs
#define BB   16
#define NS   64
#define THREADS 256
#define GAIN 0.03125f

// ---------------- workspace layout (bytes) ----------------
#define YBUF_OFF    (33554432ull)                 // after bf16 batch [512][256][128]
#define YBUF_HALF   (524288ull)                   // bf16 [16][16][1024] per parity
#define FLG_OFF     (YBUF_OFF + 2*YBUF_HALF)
#define FLG_BYTES   (4096ull)                     // [16 groups][64 waves] u32
#define XT_OFF      (FLG_OFF + FLG_BYTES)
#define XT_BYTES    (1048576ull)                  // fp32 [256][1024]
#define WS_NEED     (XT_OFF + XT_BYTES)

typedef short    s16x8 __attribute__((ext_vector_type(8)));
typedef float    f32x4 __attribute__((ext_vector_type(4)));
typedef unsigned u32x4 __attribute__((ext_vector_type(4)));

__device__ __forceinline__ unsigned short f2bf(float f) {
  unsigned u = __builtin_bit_cast(unsigned, f);
  u += 0x7fffu + ((u >> 16) & 1u);               // RTNE
  return (unsigned short)(u >> 16);
}

// ---------------- batch fp32 -> bf16 prepass ----------------
__global__ void horn_convert(const float* __restrict__ src, unsigned short* __restrict__ dst) {
  size_t gid = (size_t)blockIdx.x * 256 + threadIdx.x;
  const f32x4* s4 = reinterpret_cast<const f32x4*>(src) + gid * 2;
  f32x4 a = s4[0], b = s4[1];
  u32x4 o;
  o[0] = (unsigned)f2bf(a[0]) | ((unsigned)f2bf(a[1]) << 16);
  o[1] = (unsigned)f2bf(a[2]) | ((unsigned)f2bf(a[3]) << 16);
  o[2] = (unsigned)f2bf(b[0]) | ((unsigned)f2bf(b[1]) << 16);
  o[3] = (unsigned)f2bf(b[2]) | ((unsigned)f2bf(b[3]) << 16);
  reinterpret_cast<u32x4*>(dst)[gid] = o;
}

// ---------------- persistent recurrent kernel ----------------
// K-split: wave wv covers K in [wv*256, wv*256+256) for ALL 64 cols of the slice.
// y A-frags gathered straight from MALL into registers (no LDS staging).
// Cross-wave reduction via parity-double-buffered LDS (32 KB), 1 barrier/step.
__launch_bounds__(THREADS, 1)
__global__ void horn_persistent(const unsigned short* __restrict__ batchbf,
                                const float* __restrict__ i2h_w,
                                const float* __restrict__ i2h_b,
                                const float* __restrict__ h2h_w,
                                const float* __restrict__ h2h_b,
                                unsigned short* ybuf,     // [2][16][16][1024] bf16
                                unsigned int*  flags,     // [16][64] u32
                                float* xT)                // [256][1024] fp32
{
  __shared__ f32x4 red[2][16][64];                 // [parity][wv*4+ct][lane]
  const int tid  = threadIdx.x;
  const int lane = tid & 63;
  const int wv   = tid >> 6;          // wave 0..3 (owns K-quarter wv)
  const int blk  = blockIdx.x;
  const int ig   = blk & 15;          // batch group
  const int jg   = blk >> 4;          // n-slice
  const int l15  = lane & 15;
  const int kb   = lane >> 4;         // k-sub within fragment
  const int jc   = jg * NS + wv * 16 + l15;        // column this wave OWNS (state)

  // ---- W fragments: cols jg*64+ct*16+l15, K-quarter wv, pre-scaled by GAIN ----
  s16x8 wfrag[4][8];
  #pragma unroll
  for (int ct = 0; ct < 4; ++ct) {
    #pragma unroll
    for (int q = 0; q < 8; ++q) {
      const float* g = h2h_w + (size_t)(jg * NS + ct * 16 + l15) * NDIM + wv * 256 + q * 32 + kb * 8;
      f32x4 a = *reinterpret_cast<const f32x4*>(g);
      f32x4 b = *reinterpret_cast<const f32x4*>(g + 4);
      s16x8 v;
      v[0] = (short)f2bf(a[0]*GAIN); v[1] = (short)f2bf(a[1]*GAIN);
      v[2] = (short)f2bf(a[2]*GAIN); v[3] = (short)f2bf(a[3]*GAIN);
      v[4] = (short)f2bf(b[0]*GAIN); v[5] = (short)f2bf(b[1]*GAIN);
      v[6] = (short)f2bf(b[2]*GAIN); v[7] = (short)f2bf(b[3]*GAIN);
      wfrag[ct][q] = v;
    }
  }

  // ---- i2h B-fragments + fused bias (for OWNED column jc) ----
  s16x8 i2hf[4];
  #pragma unroll
  for (int kc = 0; kc < 4; ++kc) {
    const float* g = i2h_w + (size_t)jc * IDIM + kc * 32 + kb * 8;
    s16x8 v;
    #pragma unroll
    for (int e = 0; e < 8; ++e) v[e] = (short)f2bf(g[e]);
    i2hf[kc] = v;
  }
  const float bias = i2h_b[jc] + h2h_b[jc] * GAIN;

  // ---- batch fragments for t=0 ----
  s16x8 bfr[4];
  {
    const unsigned short* bp = batchbf + ((size_t)ig * BB + l15) * IDIM + kb * 8;
    #pragma unroll
    for (int kc = 0; kc < 4; ++kc) bfr[kc] = *reinterpret_cast<const s16x8*>(bp + kc * 32);
  }

  // ---- per-lane pointers ----
  const char* ybase = (const char*)ybuf + (size_t)ig * (BB * NDIM * 2)
                      + (size_t)l15 * 2048 + wv * 512 + kb * 16;   // gather base (parity 0)
  unsigned short* wp0 = ybuf + (size_t)ig * (BB * NDIM) + (size_t)(kb * 4) * NDIM + jc; // publish base (parity 0)
  const unsigned int* fpoll = flags + ig * 64 + lane;              // poll: one flag per lane
  unsigned int* fstore = flags + ig * 64 + jg * 4 + wv;            // my wave's flag

  float xs[4] = {0.f,0.f,0.f,0.f};
  float ys[4] = {0.f,0.f,0.f,0.f};

  for (int t = 0; t < T_STEPS; ++t) {
    // ---- poll: all 64 waves of this group have published y_t ----
    if (t > 0) {
      while (true) {
        unsigned fv;
        asm volatile("global_load_dword %0, %1, off sc0 sc1\n\t"
                     "s_waitcnt vmcnt(0)"
                     : "=v"(fv) : "v"(fpoll) : "memory");
        if (__all((int)fv >= t)) break;
      }
    }

    // ---- issue y-quarter gather straight to A-registers (no LDS) ----
    const char* gp = ybase + (size_t)(t & 1) * YBUF_HALF;
    s16x8 a0, a1, a2, a3, a4, a5, a6, a7;
    asm volatile(
      "global_load_dwordx4 %0, %8, off offset:0   sc0 sc1\n\t"
      "global_load_dwordx4 %1, %8, off offset:64  sc0 sc1\n\t"
      "global_load_dwordx4 %2, %8, off offset:128 sc0 sc1\n\t"
      "global_load_dwordx4 %3, %8, off offset:192 sc0 sc1\n\t"
      "global_load_dwordx4 %4, %8, off offset:256 sc0 sc1\n\t"
      "global_load_dwordx4 %5, %8, off offset:320 sc0 sc1\n\t"
      "global_load_dwordx4 %6, %8, off offset:384 sc0 sc1\n\t"
      "global_load_dwordx4 %7, %8, off offset:448 sc0 sc1"
      : "=&v"(a0), "=&v"(a1), "=&v"(a2), "=&v"(a3),
        "=&v"(a4), "=&v"(a5), "=&v"(a6), "=&v"(a7)
      : "v"(gp) : "memory");

    // ---- u-phase under the gather shadow: uacc = bias + batch_t @ i2h^T ----
    f32x4 uacc = {bias, bias, bias, bias};
    #pragma unroll
    for (int kc = 0; kc < 4; ++kc)
      uacc = __builtin_amdgcn_mfma_f32_16x16x32_bf16(bfr[kc], i2hf[kc], uacc, 0, 0, 0);

    asm volatile("s_waitcnt vmcnt(0)" ::: "memory");
    __builtin_amdgcn_sched_barrier(0);             // keep rec MFMAs below the wait

    // ---- rec partials: acc[ct] += y_quarter @ W^T (all in registers) ----
    f32x4 c0 = {0,0,0,0}, c1 = {0,0,0,0}, c2 = {0,0,0,0}, c3 = {0,0,0,0};
    #define RECQ(aq, q) \
      c0 = __builtin_amdgcn_mfma_f32_16x16x32_bf16(aq, wfrag[0][q], c0, 0, 0, 0); \
      c1 = __builtin_amdgcn_mfma_f32_16x16x32_bf16(aq, wfrag[1][q], c1, 0, 0, 0); \
      c2 = __builtin_amdgcn_mfma_f32_16x16x32_bf16(aq, wfrag[2][q], c2, 0, 0, 0); \
      c3 = __builtin_amdgcn_mfma_f32_16x16x32_bf16(aq, wfrag[3][q], c3, 0, 0, 0);
    RECQ(a0, 0) RECQ(a1, 1) RECQ(a2, 2) RECQ(a3, 3)
    RECQ(a4, 4) RECQ(a5, 5) RECQ(a6, 6) RECQ(a7, 7)
    #undef RECQ

    // ---- cross-wave reduction (parity LDS, contiguous = conflict-free) ----
    const int rp = t & 1;
    red[rp][wv * 4 + 0][lane] = c0;
    red[rp][wv * 4 + 1][lane] = c1;
    red[rp][wv * 4 + 2][lane] = c2;
    red[rp][wv * 4 + 3][lane] = c3;
    __syncthreads();
    f32x4 z4 = uacc;
    z4 += red[rp][0 * 4 + wv][lane];
    z4 += red[rp][1 * 4 + wv][lane];
    z4 += red[rp][2 * 4 + wv][lane];
    z4 += red[rp][3 * 4 + wv][lane];

    // ---- state update (fp32, fast tanh) ----
    unsigned yw0, yw1, yw2, yw3;
    {
      float z, e, r, th, yn;
      z = z4[0]; e = __expf(z + z); r = __builtin_amdgcn_rcpf(e + 1.0f); th = fmaf(-2.0f, r, 1.0f);
      yn = ys[0] + 0.1f*(th - xs[0] - 0.2f*ys[0]); xs[0] += 0.1f*yn; ys[0] = yn; yw0 = f2bf(yn);
      z = z4[1]; e = __expf(z + z); r = __builtin_amdgcn_rcpf(e + 1.0f); th = fmaf(-2.0f, r, 1.0f);
      yn = ys[1] + 0.1f*(th - xs[1] - 0.2f*ys[1]); xs[1] += 0.1f*yn; ys[1] = yn; yw1 = f2bf(yn);
      z = z4[2]; e = __expf(z + z); r = __builtin_amdgcn_rcpf(e + 1.0f); th = fmaf(-2.0f, r, 1.0f);
      yn = ys[2] + 0.1f*(th - xs[2] - 0.2f*ys[2]); xs[2] += 0.1f*yn; ys[2] = yn; yw2 = f2bf(yn);
      z = z4[3]; e = __expf(z + z); r = __builtin_amdgcn_rcpf(e + 1.0f); th = fmaf(-2.0f, r, 1.0f);
      yn = ys[3] + 0.1f*(th - xs[3] - 0.2f*ys[3]); xs[3] += 0.1f*yn; ys[3] = yn; yw3 = f2bf(yn);
    }

    // ---- publish y_{t+1} for OWNED column (4 rows), drain, then flag ----
    {
      unsigned short* b0 = wp0 + (size_t)((t + 1) & 1) * 262144;
      unsigned short* b1 = b0 + 2 * NDIM;
      asm volatile(
        "global_store_short %4, %0, off offset:0    sc0 sc1\n\t"
        "global_store_short %4, %1, off offset:2048 sc0 sc1\n\t"
        "global_store_short %5, %2, off offset:0    sc0 sc1\n\t"
        "global_store_short %5, %3, off offset:2048 sc0 sc1\n\t"
        "s_waitcnt vmcnt(0)"
        :
        : "v"(yw0), "v"(yw1), "v"(yw2), "v"(yw3), "v"(b0), "v"(b1)
        : "memory");
    }
    if (lane == 0) {
      unsigned nv = (unsigned)(t + 1);
      asm volatile("global_store_dword %0, %1, off sc0 sc1"
                   :: "v"(fstore), "v"(nv) : "memory");
    }

    // ---- prefetch batch for t+1 (overlaps next poll) ----
    {
      const int tn = (t + 1 < T_STEPS) ? (t + 1) : t;
      const unsigned short* bp = batchbf + ((size_t)tn * BATCH_N + ig * BB + l15) * IDIM + kb * 8;
      #pragma unroll
      for (int kc = 0; kc < 4; ++kc) bfr[kc] = *reinterpret_cast<const s16x8*>(bp + kc * 32);
    }
  }

  // ---- write x_T (owned column, 4 rows) ----
  #pragma unroll
  for (int q = 0; q < 4; ++q) {
    int row = ig * BB + kb * 4 + q;
    xT[(size_t)row * NDIM + jc] = xs[q];
  }
}

// ---------------- final readout: out = x_T @ h2o^T + b ----------------
__global__ void horn_out(const float* __restrict__ xT, const float* __restrict__ h2o_w,
                         const float* __restrict__ h2o_b, float* __restrict__ out) {
  int b = blockIdx.x;
  int lane = threadIdx.x;                  // 64 threads
  float p[ODIM];
  #pragma unroll
  for (int o = 0; o < ODIM; ++o) p[o] = 0.f;
  for (int it = 0; it < NDIM / 64; ++it) {
    int n = it * 64 + lane;
    float xv = xT[(size_t)b * NDIM + n];
    #pragma unroll
    for (int o = 0; o < ODIM; ++o) p[o] += xv * h2o_w[o * NDIM + n];
  }
  #pragma unroll
  for (int o = 0; o < ODIM; ++o) {
    float v = p[o];
    #pragma unroll
    for (int off = 32; off >= 1; off >>= 1) v += __shfl_down(v, off, 64);
    if (lane == 0) out[b * ODIM + o] = v + h2o_b[o];
  }
}

__global__ void horn_fail(float* out) {    // loud sentinel if ws too small
  int i = blockIdx.x * 256 + threadIdx.x;
  if (i < BATCH_N * ODIM) out[i] = 12345.0f;
}

extern "C" void kernel_launch(void* const* d_in, const int* in_sizes, int n_in,
                              void* d_out, int out_size, void* d_ws, size_t ws_size,
                              hipStream_t stream) {
  const float* batch = (const float*)d_in[0];
  const float* i2h_w = (const float*)d_in[1];
  const float* i2h_b = (const float*)d_in[2];
  const float* h2h_w = (const float*)d_in[3];
  const float* h2h_b = (const float*)d_in[4];
  const float* h2o_w = (const float*)d_in[5];
  const float* h2o_b = (const float*)d_in[6];
  float* out = (float*)d_out;
  char* ws = (char*)d_ws;

  if (ws_size < WS_NEED) {
    horn_fail<<<16, 256, 0, stream>>>(out);
    return;
  }

  hipMemsetAsync(ws + YBUF_OFF, 0, YBUF_HALF, stream);   // y_0 = 0 (parity 0)
  hipMemsetAsync(ws + FLG_OFF, 0, FLG_BYTES, stream);    // flags = 0

  horn_convert<<<8192, 256, 0, stream>>>(batch, (unsigned short*)(ws + 0));

  horn_persistent<<<256, THREADS, 0, stream>>>(
      (const unsigned short*)(ws + 0), i2h_w, i2h_b, h2h_w, h2h_b,
      (unsigned short*)(ws + YBUF_OFF), (unsigned int*)(ws + FLG_OFF),
      (float*)(ws + XT_OFF));

  horn_out<<<BATCH_N, 64, 0, stream>>>((const float*)(ws + XT_OFF), h2o_w, h2o_b, out);
}

// Round 5
// 2588.967 us; speedup vs baseline: 1.6420x; 1.6420x over previous
//
#include <hip/hip_runtime.h>

// ---------------- problem constants ----------------
#define T_STEPS 512
#define BATCH_N 256
#define IDIM    128
#define NDIM    1024
#define ODIM    10

// 128 WGs = 16 batch-groups (16 rows) x 8 col-slices (128 cols).
// Cross-WG y exchange: self-tagged u32 words {bf16<<16 | step_tag} in MALL
// (sc0 sc1 both ways), parity double-buffered. No flags, no drains.
#define THREADS 256
#define GAIN 0.03125f

// ---------------- workspace layout (bytes) ----------------
#define YBUF_OFF    (33554432ull)                // after bf16 batch [512][256][128]
#define YBUF_WORDS  (2ull*16*16*1024)            // u32 [parity][group][row][n]
#define XT_OFF      (YBUF_OFF + YBUF_WORDS*4ull) // 35,651,584
#define XT_BYTES    (1048576ull)                 // fp32 [256][1024]
#define WS_NEED     (XT_OFF + XT_BYTES)

typedef short    s16x8 __attribute__((ext_vector_type(8)));
typedef float    f32x4 __attribute__((ext_vector_type(4)));
typedef unsigned u32x4 __attribute__((ext_vector_type(4)));

__device__ __forceinline__ unsigned short f2bf(float f) {
  unsigned u = __builtin_bit_cast(unsigned, f);
  u += 0x7fffu + ((u >> 16) & 1u);               // RTNE
  return (unsigned short)(u >> 16);
}
__device__ __forceinline__ unsigned umin2(unsigned a, unsigned b) { return a < b ? a : b; }

// ---------------- batch fp32 -> bf16 prepass ----------------
__global__ void horn_convert(const float* __restrict__ src, unsigned short* __restrict__ dst) {
  size_t gid = (size_t)blockIdx.x * 256 + threadIdx.x;
  const f32x4* s4 = reinterpret_cast<const f32x4*>(src) + gid * 2;
  f32x4 a = s4[0], b = s4[1];
  u32x4 o;
  o[0] = (unsigned)f2bf(a[0]) | ((unsigned)f2bf(a[1]) << 16);
  o[1] = (unsigned)f2bf(a[2]) | ((unsigned)f2bf(a[3]) << 16);
  o[2] = (unsigned)f2bf(b[0]) | ((unsigned)f2bf(b[1]) << 16);
  o[3] = (unsigned)f2bf(b[2]) | ((unsigned)f2bf(b[3]) << 16);
  reinterpret_cast<u32x4*>(dst)[gid] = o;
}

// ---------------- persistent recurrent kernel ----------------
__launch_bounds__(THREADS, 1)
__global__ void horn_persistent(const unsigned short* __restrict__ batchbf,
                                const float* __restrict__ i2h_w,
                                const float* __restrict__ i2h_b,
                                const float* __restrict__ h2h_w,
                                const float* __restrict__ h2h_b,
                                unsigned* ybuf,           // u32 [2][16][16][1024]
                                float* xT)                // [256][1024] fp32
{
  __shared__ f32x4 red[2][4][8][64];                       // 64 KiB
  const int tid  = threadIdx.x;
  const int lane = tid & 63;
  const int wv   = tid >> 6;            // wave 0..3: K-quarter wv (rec), k-32-block wv (u)
  const int ig   = blockIdx.x & 15;     // batch group
  const int jg   = blockIdx.x >> 4;     // col-slice 0..7 (128 cols)
  const int l15  = lane & 15;
  const int kb   = lane >> 4;

  // ---- W fragments in VGPRs: 8 col-tiles x 8 k-frags (K-quarter wv), xGAIN ----
  s16x8 wfrag[8][8];
  #pragma unroll
  for (int ct = 0; ct < 8; ++ct) {
    #pragma unroll
    for (int kc = 0; kc < 8; ++kc) {
      const float* g = h2h_w + (size_t)(jg * 128 + ct * 16 + l15) * NDIM + wv * 256 + kc * 32 + kb * 8;
      f32x4 a = *reinterpret_cast<const f32x4*>(g);
      f32x4 b = *reinterpret_cast<const f32x4*>(g + 4);
      s16x8 v;
      v[0] = (short)f2bf(a[0]*GAIN); v[1] = (short)f2bf(a[1]*GAIN);
      v[2] = (short)f2bf(a[2]*GAIN); v[3] = (short)f2bf(a[3]*GAIN);
      v[4] = (short)f2bf(b[0]*GAIN); v[5] = (short)f2bf(b[1]*GAIN);
      v[6] = (short)f2bf(b[2]*GAIN); v[7] = (short)f2bf(b[3]*GAIN);
      wfrag[ct][kc] = v;
    }
  }

  // ---- i2h B-frags: 8 col-tiles, k-block wv (32 of 128) ----
  s16x8 i2hf[8];
  #pragma unroll
  for (int ct = 0; ct < 8; ++ct) {
    const float* g = i2h_w + (size_t)(jg * 128 + ct * 16 + l15) * IDIM + wv * 32 + kb * 8;
    s16x8 v;
    #pragma unroll
    for (int e = 0; e < 8; ++e) v[e] = (short)f2bf(g[e]);
    i2hf[ct] = v;
  }

  // ---- owned output columns (post-reduction): tiles 2wv, 2wv+1 ----
  const int c0 = jg * 128 + (2 * wv) * 16 + l15;
  const int c1 = c0 + 16;
  const float bias0 = i2h_b[c0] + GAIN * h2h_b[c0];
  const float bias1 = i2h_b[c1] + GAIN * h2h_b[c1];

  // ---- batch A-frag for t=0 (k-block wv) ----
  s16x8 bfr = *reinterpret_cast<const s16x8*>(
      batchbf + ((size_t)ig * 16 + l15) * IDIM + wv * 32 + kb * 8);

  float xs[8] = {0,0,0,0,0,0,0,0};
  float ys[8] = {0,0,0,0,0,0,0,0};

  // gather base (parity 0): row l15, k-quarter wv
  const unsigned* gbase = ybuf + ((size_t)ig * 16 + l15) * 1024 + wv * 256 + kb * 8;

  for (int t = 0; t < T_STEPS; ++t) {
    // ---- u-phase partials (k-split): c[ct] = batch_t @ i2h^T (quarter) ----
    f32x4 c0a = __builtin_amdgcn_mfma_f32_16x16x32_bf16(bfr, i2hf[0], (f32x4){0,0,0,0}, 0, 0, 0);
    f32x4 c1a = __builtin_amdgcn_mfma_f32_16x16x32_bf16(bfr, i2hf[1], (f32x4){0,0,0,0}, 0, 0, 0);
    f32x4 c2a = __builtin_amdgcn_mfma_f32_16x16x32_bf16(bfr, i2hf[2], (f32x4){0,0,0,0}, 0, 0, 0);
    f32x4 c3a = __builtin_amdgcn_mfma_f32_16x16x32_bf16(bfr, i2hf[3], (f32x4){0,0,0,0}, 0, 0, 0);
    f32x4 c4a = __builtin_amdgcn_mfma_f32_16x16x32_bf16(bfr, i2hf[4], (f32x4){0,0,0,0}, 0, 0, 0);
    f32x4 c5a = __builtin_amdgcn_mfma_f32_16x16x32_bf16(bfr, i2hf[5], (f32x4){0,0,0,0}, 0, 0, 0);
    f32x4 c6a = __builtin_amdgcn_mfma_f32_16x16x32_bf16(bfr, i2hf[6], (f32x4){0,0,0,0}, 0, 0, 0);
    f32x4 c7a = __builtin_amdgcn_mfma_f32_16x16x32_bf16(bfr, i2hf[7], (f32x4){0,0,0,0}, 0, 0, 0);

    // ---- poll+gather: self-tagged words, re-load until all tags >= t ----
    const unsigned* gp = gbase + (size_t)(t & 1) * 262144;
    u32x4 g0,g1,g2,g3,g4,g5,g6,g7,g8,g9,g10,g11,g12,g13,g14,g15;
    while (true) {
      asm volatile(
        "global_load_dwordx4 %0, %16, off offset:0 sc0 sc1\n\t"
        "global_load_dwordx4 %1, %16, off offset:16 sc0 sc1\n\t"
        "global_load_dwordx4 %2, %16, off offset:128 sc0 sc1\n\t"
        "global_load_dwordx4 %3, %16, off offset:144 sc0 sc1\n\t"
        "global_load_dwordx4 %4, %16, off offset:256 sc0 sc1\n\t"
        "global_load_dwordx4 %5, %16, off offset:272 sc0 sc1\n\t"
        "global_load_dwordx4 %6, %16, off offset:384 sc0 sc1\n\t"
        "global_load_dwordx4 %7, %16, off offset:400 sc0 sc1\n\t"
        "global_load_dwordx4 %8, %16, off offset:512 sc0 sc1\n\t"
        "global_load_dwordx4 %9, %16, off offset:528 sc0 sc1\n\t"
        "global_load_dwordx4 %10, %16, off offset:640 sc0 sc1\n\t"
        "global_load_dwordx4 %11, %16, off offset:656 sc0 sc1\n\t"
        "global_load_dwordx4 %12, %16, off offset:768 sc0 sc1\n\t"
        "global_load_dwordx4 %13, %16, off offset:784 sc0 sc1\n\t"
        "global_load_dwordx4 %14, %16, off offset:896 sc0 sc1\n\t"
        "global_load_dwordx4 %15, %16, off offset:912 sc0 sc1\n\t"
        "s_waitcnt vmcnt(0)"
        : "=&v"(g0), "=&v"(g1), "=&v"(g2), "=&v"(g3),
          "=&v"(g4), "=&v"(g5), "=&v"(g6), "=&v"(g7),
          "=&v"(g8), "=&v"(g9), "=&v"(g10), "=&v"(g11),
          "=&v"(g12), "=&v"(g13), "=&v"(g14), "=&v"(g15)
        : "v"(gp) : "memory");
      unsigned mn = 0xffffffffu;
      #define MN(v) mn = umin2(mn, umin2(umin2(v[0]&0xffffu, v[1]&0xffffu), umin2(v[2]&0xffffu, v[3]&0xffffu)));
      MN(g0) MN(g1) MN(g2) MN(g3) MN(g4) MN(g5) MN(g6) MN(g7)
      MN(g8) MN(g9) MN(g10) MN(g11) MN(g12) MN(g13) MN(g14) MN(g15)
      #undef MN
      if (__all((int)(mn >= (unsigned)t))) break;
      __builtin_amdgcn_s_sleep(2);
    }

    // ---- repack tagged u32 -> bf16 A-frags (hi16 of each word) ----
    s16x8 a0, a1, a2, a3, a4, a5, a6, a7;
    #define RPK(dst, lo, hi) { u32x4 o_; \
      o_[0] = __builtin_amdgcn_perm(lo[1], lo[0], 0x07060302u); \
      o_[1] = __builtin_amdgcn_perm(lo[3], lo[2], 0x07060302u); \
      o_[2] = __builtin_amdgcn_perm(hi[1], hi[0], 0x07060302u); \
      o_[3] = __builtin_amdgcn_perm(hi[3], hi[2], 0x07060302u); \
      dst = __builtin_bit_cast(s16x8, o_); }
    RPK(a0, g0, g1)   RPK(a1, g2, g3)   RPK(a2, g4, g5)   RPK(a3, g6, g7)
    RPK(a4, g8, g9)   RPK(a5, g10, g11) RPK(a6, g12, g13) RPK(a7, g14, g15)
    #undef RPK

    // ---- rec partials: c[ct] += y_quarter @ W^T ----
    #define RECK(ak, kc) \
      c0a = __builtin_amdgcn_mfma_f32_16x16x32_bf16(ak, wfrag[0][kc], c0a, 0, 0, 0); \
      c1a = __builtin_amdgcn_mfma_f32_16x16x32_bf16(ak, wfrag[1][kc], c1a, 0, 0, 0); \
      c2a = __builtin_amdgcn_mfma_f32_16x16x32_bf16(ak, wfrag[2][kc], c2a, 0, 0, 0); \
      c3a = __builtin_amdgcn_mfma_f32_16x16x32_bf16(ak, wfrag[3][kc], c3a, 0, 0, 0); \
      c4a = __builtin_amdgcn_mfma_f32_16x16x32_bf16(ak, wfrag[4][kc], c4a, 0, 0, 0); \
      c5a = __builtin_amdgcn_mfma_f32_16x16x32_bf16(ak, wfrag[5][kc], c5a, 0, 0, 0); \
      c6a = __builtin_amdgcn_mfma_f32_16x16x32_bf16(ak, wfrag[6][kc], c6a, 0, 0, 0); \
      c7a = __builtin_amdgcn_mfma_f32_16x16x32_bf16(ak, wfrag[7][kc], c7a, 0, 0, 0);
    RECK(a0, 0) RECK(a1, 1) RECK(a2, 2) RECK(a3, 3)
    RECK(a4, 4) RECK(a5, 5) RECK(a6, 6) RECK(a7, 7)
    #undef RECK

    // ---- cross-wave reduction (parity LDS, contiguous b128) ----
    const int rp = t & 1;
    red[rp][wv][0][lane] = c0a; red[rp][wv][1][lane] = c1a;
    red[rp][wv][2][lane] = c2a; red[rp][wv][3][lane] = c3a;
    red[rp][wv][4][lane] = c4a; red[rp][wv][5][lane] = c5a;
    red[rp][wv][6][lane] = c6a; red[rp][wv][7][lane] = c7a;
    __syncthreads();
    f32x4 z0 = red[rp][0][2*wv][lane]   + red[rp][1][2*wv][lane]
             + red[rp][2][2*wv][lane]   + red[rp][3][2*wv][lane];
    f32x4 z1 = red[rp][0][2*wv+1][lane] + red[rp][1][2*wv+1][lane]
             + red[rp][2][2*wv+1][lane] + red[rp][3][2*wv+1][lane];

    // ---- state update + self-tagged publish (fire-and-forget) ----
    const unsigned tag = (unsigned)(t + 1);
    unsigned* pb = ybuf + (size_t)((t + 1) & 1) * 262144 + (size_t)ig * 16384 + (size_t)(kb * 4) * 1024;
    #define UPD(s, r, zv, biasv, colv) { \
      float z_ = zv[r] + biasv; \
      float e_ = __expf(z_ + z_); \
      float th_ = fmaf(-2.0f, __builtin_amdgcn_rcpf(e_ + 1.0f), 1.0f); \
      int si_ = (s)*4 + (r); \
      float yn_ = ys[si_] + 0.1f*(th_ - xs[si_] - 0.2f*ys[si_]); \
      xs[si_] += 0.1f*yn_; ys[si_] = yn_; \
      unsigned w_ = ((unsigned)f2bf(yn_) << 16) | tag; \
      unsigned* ad_ = pb + (r) * 1024 + (colv); \
      asm volatile("global_store_dword %0, %1, off sc0 sc1" :: "v"(ad_), "v"(w_) : "memory"); }
    UPD(0, 0, z0, bias0, c0) UPD(0, 1, z0, bias0, c0) UPD(0, 2, z0, bias0, c0) UPD(0, 3, z0, bias0, c0)
    UPD(1, 0, z1, bias1, c1) UPD(1, 1, z1, bias1, c1) UPD(1, 2, z1, bias1, c1) UPD(1, 3, z1, bias1, c1)
    #undef UPD

    // ---- prefetch batch A-frag for t+1 (plain cached load) ----
    {
      const int tn = (t + 1 < T_STEPS) ? (t + 1) : t;
      bfr = *reinterpret_cast<const s16x8*>(
          batchbf + ((size_t)tn * BATCH_N + ig * 16 + l15) * IDIM + wv * 32 + kb * 8);
    }
  }

  // ---- write x_T (owned columns, 4 rows each) ----
  #pragma unroll
  for (int r = 0; r < 4; ++r) {
    int row = ig * 16 + kb * 4 + r;
    xT[(size_t)row * NDIM + c0] = xs[r];
    xT[(size_t)row * NDIM + c1] = xs[4 + r];
  }
}

// ---------------- final readout: out = x_T @ h2o^T + b ----------------
__global__ void horn_out(const float* __restrict__ xT, const float* __restrict__ h2o_w,
                         const float* __restrict__ h2o_b, float* __restrict__ out) {
  int b = blockIdx.x;
  int lane = threadIdx.x;                  // 64 threads
  float p[ODIM];
  #pragma unroll
  for (int o = 0; o < ODIM; ++o) p[o] = 0.f;
  for (int it = 0; it < NDIM / 64; ++it) {
    int n = it * 64 + lane;
    float xv = xT[(size_t)b * NDIM + n];
    #pragma unroll
    for (int o = 0; o < ODIM; ++o) p[o] += xv * h2o_w[o * NDIM + n];
  }
  #pragma unroll
  for (int o = 0; o < ODIM; ++o) {
    float v = p[o];
    #pragma unroll
    for (int off = 32; off >= 1; off >>= 1) v += __shfl_down(v, off, 64);
    if (lane == 0) out[b * ODIM + o] = v + h2o_b[o];
  }
}

__global__ void horn_fail(float* out) {    // loud sentinel if ws too small
  int i = blockIdx.x * 256 + threadIdx.x;
  if (i < BATCH_N * ODIM) out[i] = 12345.0f;
}

extern "C" void kernel_launch(void* const* d_in, const int* in_sizes, int n_in,
                              void* d_out, int out_size, void* d_ws, size_t ws_size,
                              hipStream_t stream) {
  const float* batch = (const float*)d_in[0];
  const float* i2h_w = (const float*)d_in[1];
  const float* i2h_b = (const float*)d_in[2];
  const float* h2h_w = (const float*)d_in[3];
  const float* h2h_b = (const float*)d_in[4];
  const float* h2o_w = (const float*)d_in[5];
  const float* h2o_b = (const float*)d_in[6];
  float* out = (float*)d_out;
  char* ws = (char*)d_ws;

  if (ws_size < WS_NEED) {
    horn_fail<<<16, 256, 0, stream>>>(out);
    return;
  }

  hipMemsetAsync(ws + YBUF_OFF, 0, YBUF_WORDS * 4, stream);  // tags=0, y_0=0 (both parities)

  horn_convert<<<8192, 256, 0, stream>>>(batch, (unsigned short*)(ws + 0));

  horn_persistent<<<128, THREADS, 0, stream>>>(
      (const unsigned short*)(ws + 0), i2h_w, i2h_b, h2h_w, h2h_b,
      (unsigned*)(ws + YBUF_OFF), (float*)(ws + XT_OFF));

  horn_out<<<BATCH_N, 64, 0, stream>>>((const float*)(ws + XT_OFF), h2o_w, h2o_b, out);
}